// Round 6
// baseline (270.703 us; speedup 1.0000x reference)
//
#include <hip/hip_runtime.h>
#include <cstdint>

#define HEADS 16
#define DH 64
#define SEQ 2048
#define BATCH 4
#define DIM 1024
#define MTOT (BATCH*SEQ)   // 8192
#define NQKV (3*DIM)       // 3072

typedef short bf16x8 __attribute__((ext_vector_type(8)));
typedef float f32x4 __attribute__((ext_vector_type(4)));
typedef float f32x16 __attribute__((ext_vector_type(16)));

__device__ __forceinline__ unsigned short f2bf(float f) {
  union { float fv; unsigned int u; } c; c.fv = f;
  unsigned int u = c.u;
  u += 0x7FFFu + ((u >> 16) & 1u);   // round-to-nearest-even
  return (unsigned short)(u >> 16);
}

// pack two fp32 -> two bf16 in one u32 via HW instruction (1 VALU op vs ~5)
// PROVEN: r1-vs-r4 A/B on attention = 11 us (cvtpk vs manual pack)
__device__ __forceinline__ unsigned int cvtpk(float lo, float hi) {
  unsigned int r;
  asm("v_cvt_pk_bf16_f32 %0, %1, %2" : "=v"(r) : "v"(lo), "v"(hi));
  return r;
}

__device__ __forceinline__ f32x4 mfma16(bf16x8 a, bf16x8 b, f32x4 c) {
  return __builtin_amdgcn_mfma_f32_16x16x32_bf16(a, b, c, 0, 0, 0);
}
__device__ __forceinline__ f32x16 mfma32(bf16x8 a, bf16x8 b, f32x16 c) {
  return __builtin_amdgcn_mfma_f32_32x32x16_bf16(a, b, c, 0, 0, 0);
}

typedef const __attribute__((address_space(1))) unsigned int* gas_ptr;
typedef __attribute__((address_space(3))) unsigned int* las_ptr;
__device__ __forceinline__ void gl2lds16(const void* g, void* l) {
  __builtin_amdgcn_global_load_lds((gas_ptr)g, (las_ptr)l, 16, 0, 0);
}

// Q pre-scale: Dh^-0.5 * log2(e)  (softmax done in exp2 domain)
#define QSCALE 0.18033688011112042f

// ---------------------------------------------------------------- cast x -> bf16
__global__ __launch_bounds__(256) void cast_f32_bf16(
    const float* __restrict__ in, unsigned short* __restrict__ out, int n4) {
  int i = blockIdx.x * blockDim.x + threadIdx.x;
  if (i >= n4) return;
  float4 v = reinterpret_cast<const float4*>(in)[i];
  uint2 o;
  o.x = (unsigned int)f2bf(v.x) | ((unsigned int)f2bf(v.y) << 16);
  o.y = (unsigned int)f2bf(v.z) | ((unsigned int)f2bf(v.w) << 16);
  reinterpret_cast<uint2*>(out)[i] = o;
}

// ------------------------------------------- transpose+cast: out[c][r] = in[r][c]
__global__ __launch_bounds__(256) void transpose_cast(
    const float* __restrict__ in, unsigned short* __restrict__ out, int R, int C) {
  __shared__ float tile[32][33];
  int c0 = blockIdx.x * 32, r0 = blockIdx.y * 32;
  int tx = threadIdx.x & 31, ty = threadIdx.x >> 5;  // ty 0..7
  for (int i = 0; i < 32; i += 8)
    tile[ty + i][tx] = in[(size_t)(r0 + ty + i) * C + c0 + tx];
  __syncthreads();
  for (int i = 0; i < 32; i += 8)
    out[(size_t)(c0 + ty + i) * R + r0 + tx] = f2bf(tile[tx][ty + i]);
}

// ------------------------------------------- V [b,h,n,d] -> Vt [b,h,d,n]
__global__ __launch_bounds__(256) void transpose_v(
    const unsigned short* __restrict__ V, unsigned short* __restrict__ Vt) {
  __shared__ unsigned short tile[64][72];
  int n0 = blockIdx.x * 64;
  size_t base = (size_t)blockIdx.y * SEQ * DH;
  int t = threadIdx.x;
  int r = t >> 2, c = (t & 3) * 8;
  *(uint4*)&tile[r][c]      = *(const uint4*)&V[base + (size_t)(n0 + r) * DH + c];
  *(uint4*)&tile[r][c + 32] = *(const uint4*)&V[base + (size_t)(n0 + r) * DH + c + 32];
  __syncthreads();
#pragma unroll
  for (int p = 0; p < 2; p++) {
    alignas(16) unsigned short tmp[8];
#pragma unroll
    for (int i = 0; i < 8; i++) tmp[i] = tile[c + p * 32 + i][r];
    *(uint4*)&Vt[base + (size_t)r * SEQ + n0 + c + p * 32] = *(uint4*)tmp;
  }
}

// ================================================================ pipelined GEMM
// 256x128 tile, BK=32, 512 threads (8 waves 4Mx2N, wave = 64x64, acc[4][4]).
// RING-4 LDS (96KB): stage tile t+3 while computing t. Buffer written at iter t
// was last READ at iter t-1; the entry barrier of t guarantees all waves are
// done with it -> no overwrite race. ONE raw s_barrier per tile; counted
// s_waitcnt vmcnt(6) (3 gl2lds/wave/tile, 2 tiles in flight) -- never drained
// to 0 in the main loop (T3+T4). Peeled tail: vmcnt(3)/vmcnt(0).
// Bank conflicts: read chunk XOR (fr>>1)&3 (2-way = free, m136); staged via
// pre-swizzled GLOBAL source (lane&3)^((lane>>3)&3) with linear gl2lds dest
// (both-sides involution, rule #21; same scheme proven correct r4/r5).
// NT = K/BK = 32 (K=1024 for both GEMMs).

#define STAGE(TT) { \
    char* _b = (char*)smem + ((TT) & 3) * 24576 + w * 1024; \
    gl2lds16(gA0 + (size_t)(TT) * 32, _b); \
    gl2lds16(gA1 + (size_t)(TT) * 32, _b + 8192); \
    gl2lds16(gB0 + (size_t)(TT) * 32, _b + 16384); }

#define WAITB(N) { \
    asm volatile("s_waitcnt vmcnt(" #N ")" ::: "memory"); \
    __builtin_amdgcn_s_barrier(); \
    __builtin_amdgcn_sched_barrier(0); }

#define GCOMPUTE(T) { \
    const unsigned short* sAt = smem + ((T) & 3) * 12288; \
    const unsigned short* sBt = sAt + 8192; \
    bf16x8 af[4], bv[4]; \
    _Pragma("unroll") \
    for (int mt = 0; mt < 4; mt++) \
      af[mt] = *reinterpret_cast<const bf16x8*>( \
          &sAt[(wr64 + mt * 16 + fr) * 32 + fchunk]); \
    _Pragma("unroll") \
    for (int nt = 0; nt < 4; nt++) \
      bv[nt] = *reinterpret_cast<const bf16x8*>( \
          &sBt[(wc64 + nt * 16 + fr) * 32 + fchunk]); \
    __builtin_amdgcn_s_setprio(1); \
    _Pragma("unroll") \
    for (int mt = 0; mt < 4; mt++) \
      _Pragma("unroll") \
      for (int nt = 0; nt < 4; nt++) \
        acc[mt][nt] = mfma16(af[mt], bv[nt], acc[mt][nt]); \
    __builtin_amdgcn_s_setprio(0); }

// common prologue for both GEMMs: thread geometry + staging pointers
#define GEMM_SETUP(Abase, Bbase) \
  const int KD = 1024; \
  int t = threadIdx.x; \
  int lane = t & 63, w = t >> 6; \
  int wr64 = (w >> 1) * 64;           /* wave rows: 4 M-waves */ \
  int wc64 = (w & 1) * 64;            /* wave cols: 2 N-waves */ \
  int fr = lane & 15, fg = lane >> 4; \
  int fchunk = (fg ^ ((fr >> 1) & 3)) * 8;   /* read-side XOR swizzle */ \
  int lr = lane >> 2; \
  int cg = ((lane & 3) ^ ((lane >> 3) & 3)) * 8;  /* pre-swizzled src chunk */ \
  const unsigned short* gA0 = (Abase) + (size_t)(m0 + w * 16 + lr) * KD + cg; \
  const unsigned short* gA1 = gA0 + (size_t)128 * KD; \
  const unsigned short* gB0 = (Bbase) + (size_t)(n0 + w * 16 + lr) * KD + cg; \
  f32x4 acc[4][4]; \
  _Pragma("unroll") \
  for (int i = 0; i < 4; i++) \
    _Pragma("unroll") \
    for (int j = 0; j < 4; j++) { f32x4 z = {0.f, 0.f, 0.f, 0.f}; acc[i][j] = z; }

#define GEMM_MAINLOOP \
  STAGE(0); STAGE(1); STAGE(2); \
  for (int kt = 0; kt < 30; ++kt) { \
    WAITB(6); \
    if (kt < 29) STAGE(kt + 3); \
    GCOMPUTE(kt); \
  } \
  WAITB(3); \
  GCOMPUTE(30); \
  WAITB(0); \
  GCOMPUTE(31);

// ---------------------------------------------------------------- QKV GEMM
__global__ __launch_bounds__(512, 2) void gemm_qkv(
    const unsigned short* __restrict__ A, const unsigned short* __restrict__ Bt,
    unsigned short* __restrict__ Q, unsigned short* __restrict__ K,
    unsigned short* __restrict__ V) {
  __shared__ unsigned short smem[4 * 12288];   // 96KB: 4 x (A 16KB + B 8KB)
  // XCD-bijective swizzle: nwg = 24*32 = 768, %8==0, cpx=96
  int gid = blockIdx.x + 24 * blockIdx.y;      // gridDim = (24, 32)
  int swz = (gid & 7) * 96 + (gid >> 3);
  int m0 = (swz / 24) * 256;
  int n0 = (swz % 24) * 128;

  GEMM_SETUP(A, Bt)
  GEMM_MAINLOOP

  // epilogue: scatter to q/k/v [b][h][n][d] (hoisted addressing, r5-proven)
  int rowq = fg * 4;
  int b = m0 >> 11;                        // block-uniform (256 | 2048)
  int nrow0 = (m0 & 2047) + wr64 + rowq;
#pragma unroll
  for (int nt = 0; nt < 4; nt++) {
    int ncb = n0 + wc64 + nt * 16;
    int which = ncb >> 10;
    int hdb = ncb & 1023;
    int hh = hdb >> 6;
    int dcol = (hdb & 63) + fr;
    unsigned short* dst = (which == 0) ? Q : (which == 1 ? K : V);
    size_t cbase = ((size_t)(b * HEADS + hh) * SEQ) * DH + dcol;
#pragma unroll
    for (int mt = 0; mt < 4; mt++) {
      f32x4 av = acc[mt][nt];
      if (which == 0) {
        av[0] *= QSCALE; av[1] *= QSCALE; av[2] *= QSCALE; av[3] *= QSCALE;
      }
      size_t idx = cbase + (size_t)(nrow0 + mt * 16) * DH;
      unsigned int u0 = cvtpk(av[0], av[1]);
      unsigned int u1 = cvtpk(av[2], av[3]);
      dst[idx]          = (unsigned short)u0;
      dst[idx + DH]     = (unsigned short)(u0 >> 16);
      dst[idx + 2 * DH] = (unsigned short)u1;
      dst[idx + 3 * DH] = (unsigned short)(u1 >> 16);
    }
  }
}

// ---------------------------------------------------------------- out-proj GEMM
__global__ __launch_bounds__(512, 2) void gemm_out(
    const unsigned short* __restrict__ A, const unsigned short* __restrict__ Bt,
    const float* __restrict__ bias, float* __restrict__ C) {
  __shared__ unsigned short smem[4 * 12288];   // 96KB
  // XCD-bijective swizzle: nwg = 8*32 = 256, %8==0, cpx=32
  int gid = blockIdx.x + 8 * blockIdx.y;       // gridDim = (8, 32)
  int swz = (gid & 7) * 32 + (gid >> 3);
  int m0 = (swz / 8) * 256;
  int n0 = (swz % 8) * 128;

  GEMM_SETUP(A, Bt)
  GEMM_MAINLOOP

  // epilogue: bias add, f32 out
  int rowq = fg * 4;
#pragma unroll
  for (int nt = 0; nt < 4; nt++) {
    int ncol = n0 + wc64 + nt * 16 + fr;
    float bb = bias[ncol];
    size_t cb = (size_t)(m0 + wr64 + rowq) * DIM + ncol;
#pragma unroll
    for (int mt = 0; mt < 4; mt++)
#pragma unroll
      for (int r = 0; r < 4; r++)
        C[cb + (size_t)(mt * 16 + r) * DIM] = acc[mt][nt][r] + bb;
  }
}

// ---------------------------------------------------------------- flash attention
// ROUND-5 EXACT (81.5 us, 843 TF): cvtpk packing, single-buffer, 2 barriers/tile.
// grid (SEQ/128, HEADS, BATCH) via XCD-grouped gid remap; 4 waves x 32 q-rows.
#define LDA 68

__global__ __launch_bounds__(256, 4) void attention(
    const unsigned short* __restrict__ Qg, const unsigned short* __restrict__ Kg,
    const unsigned short* __restrict__ Vtg, unsigned short* __restrict__ Og) {
  __shared__ unsigned short smem[2 * 64 * 72];   // 18432 B
  unsigned short* sK  = smem;
  unsigned short* sVt = smem + 64 * LDA;

  int gid = blockIdx.x + 16 * (blockIdx.y + 16 * blockIdx.z);  // 0..1023
  int qb   = (gid >> 3) & 15;
  int pair = ((gid & 7) << 3) | (gid >> 7);   // xcd*8 + group
  int h = pair & 15, b = pair >> 4;

  size_t base = (size_t)(b * HEADS + h) * SEQ * DH;
  const unsigned short* Q = Qg + base;
  const unsigned short* K = Kg + base;
  const unsigned short* Vt = Vtg + base;
  int t = threadIdx.x, lane = t & 63, w = t >> 6;
  int m = lane & 31, kh = lane >> 5;
  int q0 = qb * 128 + w * 32;

  bf16x8 qf[4];
#pragma unroll
  for (int kt = 0; kt < 4; kt++)
    qf[kt] = *reinterpret_cast<const bf16x8*>(
        &Q[(size_t)(q0 + m) * DH + kt * 16 + kh * 8]);

  f32x16 oaccT[2];   // [dhalf], C layout: row=d', col=qrow
#pragma unroll
  for (int dh = 0; dh < 2; dh++)
#pragma unroll
    for (int i = 0; i < 16; i++) oaccT[dh][i] = 0.f;
  float rs = 0.f;

  int sr = t >> 2, sc = (t & 3) * 8;

  for (int j0 = 0; j0 < SEQ; j0 += 64) {
    {
      uint4 a0 = *(const uint4*)&K[(size_t)(j0 + sr) * DH + sc];
      uint4 a1 = *(const uint4*)&K[(size_t)(j0 + sr) * DH + sc + 32];
      uint4 b0 = *(const uint4*)&Vt[(size_t)sr * SEQ + j0 + sc];
      uint4 b1 = *(const uint4*)&Vt[(size_t)sr * SEQ + j0 + sc + 32];
      unsigned short* pk0 = &sK[sr * LDA + sc];
      unsigned short* pk1 = &sK[sr * LDA + sc + 32];
      unsigned short* pv0 = &sVt[sr * LDA + sc];
      unsigned short* pv1 = &sVt[sr * LDA + sc + 32];
      *(uint2*)pk0       = make_uint2(a0.x, a0.y);
      *(uint2*)(pk0 + 4) = make_uint2(a0.z, a0.w);
      *(uint2*)pk1       = make_uint2(a1.x, a1.y);
      *(uint2*)(pk1 + 4) = make_uint2(a1.z, a1.w);
      *(uint2*)pv0       = make_uint2(b0.x, b0.y);
      *(uint2*)(pv0 + 4) = make_uint2(b0.z, b0.w);
      *(uint2*)pv1       = make_uint2(b1.x, b1.y);
      *(uint2*)(pv1 + 4) = make_uint2(b1.z, b1.w);
    }
    __syncthreads();

    unsigned int pp[8][2];
#pragma unroll
    for (int jt = 0; jt < 2; jt++) {
      bf16x8 kf[4];
#pragma unroll
      for (int kt = 0; kt < 4; kt++) {
        union { uint2 u[2]; bf16x8 v; } kc;
        const unsigned short* p = &sK[(jt * 32 + m) * LDA + (2 * kt + kh) * 8];
        kc.u[0] = *(const uint2*)p;
        kc.u[1] = *(const uint2*)(p + 4);
        kf[kt] = kc.v;
      }
      f32x16 s;
#pragma unroll
      for (int i = 0; i < 16; i++) s[i] = 0.f;
#pragma unroll
      for (int kt = 0; kt < 4; kt++)
        s = mfma32(kf[kt], qf[kt], s);
      float e[16];
#pragma unroll
      for (int i = 0; i < 16; i++) e[i] = __builtin_amdgcn_exp2f(s[i]);
      float t0 = (e[0] + e[1]) + (e[2] + e[3]);
      float t1 = (e[4] + e[5]) + (e[6] + e[7]);
      float t2 = (e[8] + e[9]) + (e[10] + e[11]);
      float t3 = (e[12] + e[13]) + (e[14] + e[15]);
      rs += (t0 + t1) + (t2 + t3);
#pragma unroll
      for (int sl = 0; sl < 4; sl++) {
        pp[4 * jt + sl][0] = cvtpk(e[4 * sl + 0], e[4 * sl + 1]);
        pp[4 * jt + sl][1] = cvtpk(e[4 * sl + 2], e[4 * sl + 3]);
      }
    }

#pragma unroll
    for (int kb = 0; kb < 4; kb++) {
#pragma unroll
      for (int dh = 0; dh < 2; dh++) {
        union { uint2 u[2]; bf16x8 v; } ac;
        const unsigned short* p = &sVt[(32 * dh + m) * LDA + 16 * kb + 4 * kh];
        ac.u[0] = *(const uint2*)p;
        ac.u[1] = *(const uint2*)(p + 8);
        union { unsigned int u[4]; bf16x8 v; } bc;
        bc.u[0] = pp[2 * kb][0];
        bc.u[1] = pp[2 * kb][1];
        bc.u[2] = pp[2 * kb + 1][0];
        bc.u[3] = pp[2 * kb + 1][1];
        oaccT[dh] = mfma32(ac.v, bc.v, oaccT[dh]);
      }
    }
    __syncthreads();
  }

  float inv;
  {
    float tot = rs + __shfl_xor(rs, 32);
    inv = 1.0f / tot;
  }

  unsigned int* ew = (unsigned int*)smem + (size_t)w * 32 * 36;
#pragma unroll
  for (int dh = 0; dh < 2; dh++)
#pragma unroll
    for (int sl = 0; sl < 4; sl++) {
      unsigned int u0 = cvtpk(oaccT[dh][4 * sl + 0] * inv, oaccT[dh][4 * sl + 1] * inv);
      unsigned int u1 = cvtpk(oaccT[dh][4 * sl + 2] * inv, oaccT[dh][4 * sl + 3] * inv);
      uint2 pk; pk.x = u0; pk.y = u1;
      *(uint2*)&ew[m * 36 + 16 * dh + 4 * sl + 2 * kh] = pk;
    }
  {
    int mr = lane >> 3, ch = lane & 7;
#pragma unroll
    for (int it = 0; it < 4; it++) {
      uint4 vv = *(const uint4*)&ew[(8 * it + mr) * 36 + ch * 4];
      int n = q0 + 8 * it + mr;
      *(uint4*)&Og[((size_t)(b * SEQ + n)) * DIM + h * DH + ch * 8] = vv;
    }
  }
}

// ---------------------------------------------------------------- launch
extern "C" void kernel_launch(void* const* d_in, const int* in_sizes, int n_in,
                              void* d_out, int out_size, void* d_ws, size_t ws_size,
                              hipStream_t stream) {
  const float* x     = (const float*)d_in[0];  // [4,2048,1024]
  const float* w_qkv = (const float*)d_in[1];  // [1024,3072]
  const float* w_out = (const float*)d_in[2];  // [1024,1024]
  const float* b_out = (const float*)d_in[3];  // [1024]
  float* out = (float*)d_out;                  // [4,2048,1024]

  char* ws = (char*)d_ws;
  unsigned short* xb     = (unsigned short*)ws; ws += (size_t)MTOT * DIM * 2;
  unsigned short* wqkv_t = (unsigned short*)ws; ws += (size_t)NQKV * DIM * 2;
  unsigned short* wout_t = (unsigned short*)ws; ws += (size_t)DIM * DIM * 2;
  unsigned short* qb_    = (unsigned short*)ws; ws += (size_t)BATCH * HEADS * SEQ * DH * 2;
  unsigned short* kb_    = (unsigned short*)ws; ws += (size_t)BATCH * HEADS * SEQ * DH * 2;
  unsigned short* vb_    = (unsigned short*)ws; ws += (size_t)BATCH * HEADS * SEQ * DH * 2;
  unsigned short* attnb  = (unsigned short*)ws; ws += (size_t)MTOT * DIM * 2;
  unsigned short* vt_    = xb;  // alias: xb dead after gemm_qkv, same size (16.8MB)

  // 1. casts / transposes
  cast_f32_bf16<<<(MTOT * DIM / 4 + 255) / 256, 256, 0, stream>>>(x, xb, MTOT * DIM / 4);
  transpose_cast<<<dim3(NQKV / 32, DIM / 32), 256, 0, stream>>>(w_qkv, wqkv_t, DIM, NQKV);
  transpose_cast<<<dim3(DIM / 32, DIM / 32), 256, 0, stream>>>(w_out, wout_t, DIM, DIM);

  // 2. QKV projection — ring-4 pipelined 256x128 (768 blocks = 3.0 CU-rounds)
  gemm_qkv<<<dim3(24, 32), 512, 0, stream>>>(xb, wqkv_t, qb_, kb_, vb_);

  // 3. V -> V^T  [b,h,d,n]   (xb is dead now; vt_ aliases it)
  transpose_v<<<dim3(SEQ / 64, BATCH * HEADS), 256, 0, stream>>>(vb_, vt_);

  // 4. flash attention (register-resident P, round-5 proven structure)
  attention<<<dim3(SEQ / 128, HEADS, BATCH), 256, 0, stream>>>(qb_, kb_, vt_, attnb);

  // 5. output projection — ring-4 pipelined 256x128 (256 blocks = 1.0 CU-round)
  gemm_out<<<dim3(8, 32), 512, 0, stream>>>(attnb, wout_t, b_out, out);
}

// Round 7
// 264.793 us; speedup vs baseline: 1.0223x; 1.0223x over previous
//
#include <hip/hip_runtime.h>
#include <cstdint>

#define HEADS 16
#define DH 64
#define SEQ 2048
#define BATCH 4
#define DIM 1024
#define MTOT (BATCH*SEQ)   // 8192
#define NQKV (3*DIM)       // 3072

typedef short bf16x8 __attribute__((ext_vector_type(8)));
typedef float f32x4 __attribute__((ext_vector_type(4)));
typedef float f32x16 __attribute__((ext_vector_type(16)));

__device__ __forceinline__ unsigned short f2bf(float f) {
  union { float fv; unsigned int u; } c; c.fv = f;
  unsigned int u = c.u;
  u += 0x7FFFu + ((u >> 16) & 1u);   // round-to-nearest-even
  return (unsigned short)(u >> 16);
}

// pack two fp32 -> two bf16 in one u32 via HW instruction (1 VALU op vs ~5)
// PROVEN: r1-vs-r4 A/B on attention = 11 us (cvtpk vs manual pack)
__device__ __forceinline__ unsigned int cvtpk(float lo, float hi) {
  unsigned int r;
  asm("v_cvt_pk_bf16_f32 %0, %1, %2" : "=v"(r) : "v"(lo), "v"(hi));
  return r;
}

__device__ __forceinline__ f32x4 mfma16(bf16x8 a, bf16x8 b, f32x4 c) {
  return __builtin_amdgcn_mfma_f32_16x16x32_bf16(a, b, c, 0, 0, 0);
}
__device__ __forceinline__ f32x16 mfma32(bf16x8 a, bf16x8 b, f32x16 c) {
  return __builtin_amdgcn_mfma_f32_32x32x16_bf16(a, b, c, 0, 0, 0);
}

typedef const __attribute__((address_space(1))) unsigned int* gas_ptr;
typedef __attribute__((address_space(3))) unsigned int* las_ptr;
__device__ __forceinline__ void gl2lds16(const void* g, void* l) {
  __builtin_amdgcn_global_load_lds((gas_ptr)g, (las_ptr)l, 16, 0, 0);
}

// Q pre-scale: Dh^-0.5 * log2(e)  (softmax done in exp2 domain)
#define QSCALE 0.18033688011112042f

// ---------------------------------------------------------------- cast x -> bf16
__global__ __launch_bounds__(256) void cast_f32_bf16(
    const float* __restrict__ in, unsigned short* __restrict__ out, int n4) {
  int i = blockIdx.x * blockDim.x + threadIdx.x;
  if (i >= n4) return;
  float4 v = reinterpret_cast<const float4*>(in)[i];
  uint2 o;
  o.x = (unsigned int)f2bf(v.x) | ((unsigned int)f2bf(v.y) << 16);
  o.y = (unsigned int)f2bf(v.z) | ((unsigned int)f2bf(v.w) << 16);
  reinterpret_cast<uint2*>(out)[i] = o;
}

// ------------------------------------------- transpose+cast: out[c][r] = in[r][c]
__global__ __launch_bounds__(256) void transpose_cast(
    const float* __restrict__ in, unsigned short* __restrict__ out, int R, int C) {
  __shared__ float tile[32][33];
  int c0 = blockIdx.x * 32, r0 = blockIdx.y * 32;
  int tx = threadIdx.x & 31, ty = threadIdx.x >> 5;  // ty 0..7
  for (int i = 0; i < 32; i += 8)
    tile[ty + i][tx] = in[(size_t)(r0 + ty + i) * C + c0 + tx];
  __syncthreads();
  for (int i = 0; i < 32; i += 8)
    out[(size_t)(c0 + ty + i) * R + r0 + tx] = f2bf(tile[tx][ty + i]);
}

// ---------------------------------------------------------------- QKV GEMM
// r5-proven: m97 structure, BK=64, XOR-swizzled tiles (both-sides pattern),
// hoisted epilogue. ROUND-7: V is written TRANSPOSED ([b,h,d,n]) directly —
// the 4 acc values per fragment are consecutive n in V^T, so 4x2B scattered
// stores merge into one 8B store, and the separate transpose_v kernel
// (33.6MB of traffic + launch) is eliminated.
#define BM 128
#define BN 128
#define BK 64

__global__ __launch_bounds__(256) void gemm_qkv(
    const unsigned short* __restrict__ A, const unsigned short* __restrict__ Bt,
    unsigned short* __restrict__ Q, unsigned short* __restrict__ K,
    unsigned short* __restrict__ V) {
  __shared__ unsigned short sA[BM * BK];
  __shared__ unsigned short sB[BN * BK];
  const int KD = 1024;
  // XCD-bijective swizzle (nwg = 24*64 = 1536, %8==0)
  int gid = blockIdx.x + 24 * blockIdx.y;      // gridDim.x == 24
  int swz = (gid & 7) * 192 + (gid >> 3);      // cpx = 1536/8
  int m0 = (swz / 24) * BM;
  int n0 = (swz % 24) * BN;
  int t = threadIdx.x;
  int lane = t & 63, w = t >> 6;
  int wm = (w >> 1) * 64, wn = (w & 1) * 64;
  int fr = lane & 15, fg = lane >> 4;

  // staging: wave w, issue i covers rows i*32 + w*8 + (lane>>3);
  // global col chunk = (lane&7) ^ (lane>>3)  (pre-swizzled source)
  int srow = w * 8 + (lane >> 3);
  int scol = ((lane & 7) ^ (lane >> 3)) * 8;
  const unsigned short* gA = &A[(size_t)(m0 + srow) * KD + scol];
  const unsigned short* gB = &Bt[(size_t)(n0 + srow) * KD + scol];
  char* lA = (char*)sA + w * 1024;   // + i*4096 per issue; lane*16 implicit
  char* lB = (char*)sB + w * 1024;

  f32x4 acc[4][4];
#pragma unroll
  for (int i = 0; i < 4; i++)
#pragma unroll
    for (int j = 0; j < 4; j++) { f32x4 z = {0.f, 0.f, 0.f, 0.f}; acc[i][j] = z; }

  for (int k0 = 0; k0 < KD; k0 += BK) {
#pragma unroll
    for (int i = 0; i < 4; i++) {
      gl2lds16(gA + (size_t)i * 32 * KD + k0, lA + i * 4096);
      gl2lds16(gB + (size_t)i * 32 * KD + k0, lB + i * 4096);
    }
    __syncthreads();
#pragma unroll
    for (int ks = 0; ks < 2; ks++) {
      bf16x8 af[4], bfr[4];
#pragma unroll
      for (int mt = 0; mt < 4; mt++)
        af[mt] = *reinterpret_cast<const bf16x8*>(
            &sA[(wm + mt * 16 + fr) * BK + (((ks * 4 + fg) ^ (fr & 7)) * 8)]);
#pragma unroll
      for (int nt = 0; nt < 4; nt++)
        bfr[nt] = *reinterpret_cast<const bf16x8*>(
            &sB[(wn + nt * 16 + fr) * BK + (((ks * 4 + fg) ^ (fr & 7)) * 8)]);
#pragma unroll
      for (int mt = 0; mt < 4; mt++)
#pragma unroll
        for (int nt = 0; nt < 4; nt++)
          acc[mt][nt] = mfma16(af[mt], bfr[nt], acc[mt][nt]);
    }
    __syncthreads();
  }

  // epilogue: Q,K -> [b][h][n][d]; V -> TRANSPOSED [b][h][d][n] (8B stores)
  int rowq = (lane >> 4) * 4;
  int b = m0 >> 11;                       // block-uniform (BM=128 | 2048)
  int nrow0 = (m0 & 2047) + wm + rowq;    // + mt*16, no wrap within block
#pragma unroll
  for (int nt = 0; nt < 4; nt++) {
    int ncb = n0 + wn + nt * 16;          // lane-uniform column base
    int which = ncb >> 10;                // uniform: fr<16 can't cross 1024
    int hdb = ncb & 1023;
    int hh = hdb >> 6;                    // uniform: hdb%64<=48, +fr<=63
    int dcol = (hdb & 63) + fr;
    if (which == 2) {
      // V^T: row = d (dcol), col = n (nrow0 + mt*16 + {0..3} consecutive)
      size_t vtb = ((size_t)(b * HEADS + hh) * DH + dcol) * SEQ + nrow0;
#pragma unroll
      for (int mt = 0; mt < 4; mt++) {
        f32x4 av = acc[mt][nt];
        uint2 pk;
        pk.x = cvtpk(av[0], av[1]);
        pk.y = cvtpk(av[2], av[3]);
        *(uint2*)&V[vtb + mt * 16] = pk;
      }
    } else {
      unsigned short* dst = (which == 0) ? Q : K;
      size_t cbase = ((size_t)(b * HEADS + hh) * SEQ) * DH + dcol;
#pragma unroll
      for (int mt = 0; mt < 4; mt++) {
        f32x4 av = acc[mt][nt];
        if (which == 0) {                 // uniform branch (Q pre-scale)
          av[0] *= QSCALE; av[1] *= QSCALE; av[2] *= QSCALE; av[3] *= QSCALE;
        }
        size_t idx = cbase + (size_t)(nrow0 + mt * 16) * DH;
        unsigned int u0 = cvtpk(av[0], av[1]);
        unsigned int u1 = cvtpk(av[2], av[3]);
        dst[idx]          = (unsigned short)u0;
        dst[idx + DH]     = (unsigned short)(u0 >> 16);
        dst[idx + 2 * DH] = (unsigned short)u1;
        dst[idx + 3 * DH] = (unsigned short)(u1 >> 16);
      }
    }
  }
}

// ---------------------------------------------------------------- out-proj GEMM
__global__ __launch_bounds__(256) void gemm_out(
    const unsigned short* __restrict__ A, const unsigned short* __restrict__ Bt,
    const float* __restrict__ bias, float* __restrict__ C) {
  __shared__ unsigned short sA[BM * BK];
  __shared__ unsigned short sB[BN * BK];
  const int KD = 1024;
  // XCD-bijective swizzle (nwg = 8*64 = 512, %8==0)
  int gid = blockIdx.x + 8 * blockIdx.y;       // gridDim.x == 8
  int swz = (gid & 7) * 64 + (gid >> 3);       // cpx = 512/8
  int m0 = (swz / 8) * BM;
  int n0 = (swz % 8) * BN;
  int t = threadIdx.x;
  int lane = t & 63, w = t >> 6;
  int wm = (w >> 1) * 64, wn = (w & 1) * 64;
  int fr = lane & 15, fg = lane >> 4;

  int srow = w * 8 + (lane >> 3);
  int scol = ((lane & 7) ^ (lane >> 3)) * 8;
  const unsigned short* gA = &A[(size_t)(m0 + srow) * KD + scol];
  const unsigned short* gB = &Bt[(size_t)(n0 + srow) * KD + scol];
  char* lA = (char*)sA + w * 1024;
  char* lB = (char*)sB + w * 1024;

  f32x4 acc[4][4];
#pragma unroll
  for (int i = 0; i < 4; i++)
#pragma unroll
    for (int j = 0; j < 4; j++) { f32x4 z = {0.f, 0.f, 0.f, 0.f}; acc[i][j] = z; }

  for (int k0 = 0; k0 < KD; k0 += BK) {
#pragma unroll
    for (int i = 0; i < 4; i++) {
      gl2lds16(gA + (size_t)i * 32 * KD + k0, lA + i * 4096);
      gl2lds16(gB + (size_t)i * 32 * KD + k0, lB + i * 4096);
    }
    __syncthreads();
#pragma unroll
    for (int ks = 0; ks < 2; ks++) {
      bf16x8 af[4], bfr[4];
#pragma unroll
      for (int mt = 0; mt < 4; mt++)
        af[mt] = *reinterpret_cast<const bf16x8*>(
            &sA[(wm + mt * 16 + fr) * BK + (((ks * 4 + fg) ^ (fr & 7)) * 8)]);
#pragma unroll
      for (int nt = 0; nt < 4; nt++)
        bfr[nt] = *reinterpret_cast<const bf16x8*>(
            &sB[(wn + nt * 16 + fr) * BK + (((ks * 4 + fg) ^ (fr & 7)) * 8)]);
#pragma unroll
      for (int mt = 0; mt < 4; mt++)
#pragma unroll
        for (int nt = 0; nt < 4; nt++)
          acc[mt][nt] = mfma16(af[mt], bfr[nt], acc[mt][nt]);
    }
    __syncthreads();
  }

  // epilogue: hoisted addressing; bias loaded once per nt
  int rowq = (lane >> 4) * 4;
#pragma unroll
  for (int nt = 0; nt < 4; nt++) {
    int ncol = n0 + wn + nt * 16 + fr;
    float bb = bias[ncol];
    size_t cb = (size_t)(m0 + wm + rowq) * DIM + ncol;
#pragma unroll
    for (int mt = 0; mt < 4; mt++)
#pragma unroll
      for (int r = 0; r < 4; r++)
        C[cb + (size_t)(mt * 16 + r) * DIM] = acc[mt][nt][r] + bb;
  }
}

// ---------------------------------------------------------------- flash attention
// ROUND-5 EXACT (81.5/79.7 us across runs): cvtpk packing, single-buffer,
// 2 barriers/tile. grid (SEQ/128, HEADS, BATCH) via XCD-grouped gid remap.
#define LDA 68

__global__ __launch_bounds__(256, 4) void attention(
    const unsigned short* __restrict__ Qg, const unsigned short* __restrict__ Kg,
    const unsigned short* __restrict__ Vtg, unsigned short* __restrict__ Og) {
  __shared__ unsigned short smem[2 * 64 * 72];   // 18432 B
  unsigned short* sK  = smem;
  unsigned short* sVt = smem + 64 * LDA;

  int gid = blockIdx.x + 16 * (blockIdx.y + 16 * blockIdx.z);  // 0..1023
  int qb   = (gid >> 3) & 15;
  int pair = ((gid & 7) << 3) | (gid >> 7);   // xcd*8 + group
  int h = pair & 15, b = pair >> 4;

  size_t base = (size_t)(b * HEADS + h) * SEQ * DH;
  const unsigned short* Q = Qg + base;
  const unsigned short* K = Kg + base;
  const unsigned short* Vt = Vtg + base;
  int t = threadIdx.x, lane = t & 63, w = t >> 6;
  int m = lane & 31, kh = lane >> 5;
  int q0 = qb * 128 + w * 32;

  bf16x8 qf[4];
#pragma unroll
  for (int kt = 0; kt < 4; kt++)
    qf[kt] = *reinterpret_cast<const bf16x8*>(
        &Q[(size_t)(q0 + m) * DH + kt * 16 + kh * 8]);

  f32x16 oaccT[2];   // [dhalf], C layout: row=d', col=qrow
#pragma unroll
  for (int dh = 0; dh < 2; dh++)
#pragma unroll
    for (int i = 0; i < 16; i++) oaccT[dh][i] = 0.f;
  float rs = 0.f;

  int sr = t >> 2, sc = (t & 3) * 8;

  for (int j0 = 0; j0 < SEQ; j0 += 64) {
    {
      uint4 a0 = *(const uint4*)&K[(size_t)(j0 + sr) * DH + sc];
      uint4 a1 = *(const uint4*)&K[(size_t)(j0 + sr) * DH + sc + 32];
      uint4 b0 = *(const uint4*)&Vt[(size_t)sr * SEQ + j0 + sc];
      uint4 b1 = *(const uint4*)&Vt[(size_t)sr * SEQ + j0 + sc + 32];
      unsigned short* pk0 = &sK[sr * LDA + sc];
      unsigned short* pk1 = &sK[sr * LDA + sc + 32];
      unsigned short* pv0 = &sVt[sr * LDA + sc];
      unsigned short* pv1 = &sVt[sr * LDA + sc + 32];
      *(uint2*)pk0       = make_uint2(a0.x, a0.y);
      *(uint2*)(pk0 + 4) = make_uint2(a0.z, a0.w);
      *(uint2*)pk1       = make_uint2(a1.x, a1.y);
      *(uint2*)(pk1 + 4) = make_uint2(a1.z, a1.w);
      *(uint2*)pv0       = make_uint2(b0.x, b0.y);
      *(uint2*)(pv0 + 4) = make_uint2(b0.z, b0.w);
      *(uint2*)pv1       = make_uint2(b1.x, b1.y);
      *(uint2*)(pv1 + 4) = make_uint2(b1.z, b1.w);
    }
    __syncthreads();

    unsigned int pp[8][2];
#pragma unroll
    for (int jt = 0; jt < 2; jt++) {
      bf16x8 kf[4];
#pragma unroll
      for (int kt = 0; kt < 4; kt++) {
        union { uint2 u[2]; bf16x8 v; } kc;
        const unsigned short* p = &sK[(jt * 32 + m) * LDA + (2 * kt + kh) * 8];
        kc.u[0] = *(const uint2*)p;
        kc.u[1] = *(const uint2*)(p + 4);
        kf[kt] = kc.v;
      }
      f32x16 s;
#pragma unroll
      for (int i = 0; i < 16; i++) s[i] = 0.f;
#pragma unroll
      for (int kt = 0; kt < 4; kt++)
        s = mfma32(kf[kt], qf[kt], s);
      float e[16];
#pragma unroll
      for (int i = 0; i < 16; i++) e[i] = __builtin_amdgcn_exp2f(s[i]);
      float t0 = (e[0] + e[1]) + (e[2] + e[3]);
      float t1 = (e[4] + e[5]) + (e[6] + e[7]);
      float t2 = (e[8] + e[9]) + (e[10] + e[11]);
      float t3 = (e[12] + e[13]) + (e[14] + e[15]);
      rs += (t0 + t1) + (t2 + t3);
#pragma unroll
      for (int sl = 0; sl < 4; sl++) {
        pp[4 * jt + sl][0] = cvtpk(e[4 * sl + 0], e[4 * sl + 1]);
        pp[4 * jt + sl][1] = cvtpk(e[4 * sl + 2], e[4 * sl + 3]);
      }
    }

#pragma unroll
    for (int kb = 0; kb < 4; kb++) {
#pragma unroll
      for (int dh = 0; dh < 2; dh++) {
        union { uint2 u[2]; bf16x8 v; } ac;
        const unsigned short* p = &sVt[(32 * dh + m) * LDA + 16 * kb + 4 * kh];
        ac.u[0] = *(const uint2*)p;
        ac.u[1] = *(const uint2*)(p + 8);
        union { unsigned int u[4]; bf16x8 v; } bc;
        bc.u[0] = pp[2 * kb][0];
        bc.u[1] = pp[2 * kb][1];
        bc.u[2] = pp[2 * kb + 1][0];
        bc.u[3] = pp[2 * kb + 1][1];
        oaccT[dh] = mfma32(ac.v, bc.v, oaccT[dh]);
      }
    }
    __syncthreads();
  }

  float inv;
  {
    float tot = rs + __shfl_xor(rs, 32);
    inv = 1.0f / tot;
  }

  unsigned int* ew = (unsigned int*)smem + (size_t)w * 32 * 36;
#pragma unroll
  for (int dh = 0; dh < 2; dh++)
#pragma unroll
    for (int sl = 0; sl < 4; sl++) {
      unsigned int u0 = cvtpk(oaccT[dh][4 * sl + 0] * inv, oaccT[dh][4 * sl + 1] * inv);
      unsigned int u1 = cvtpk(oaccT[dh][4 * sl + 2] * inv, oaccT[dh][4 * sl + 3] * inv);
      uint2 pk; pk.x = u0; pk.y = u1;
      *(uint2*)&ew[m * 36 + 16 * dh + 4 * sl + 2 * kh] = pk;
    }
  {
    int mr = lane >> 3, ch = lane & 7;
#pragma unroll
    for (int it = 0; it < 4; it++) {
      uint4 vv = *(const uint4*)&ew[(8 * it + mr) * 36 + ch * 4];
      int n = q0 + 8 * it + mr;
      *(uint4*)&Og[((size_t)(b * SEQ + n)) * DIM + h * DH + ch * 8] = vv;
    }
  }
}

// ---------------------------------------------------------------- launch
extern "C" void kernel_launch(void* const* d_in, const int* in_sizes, int n_in,
                              void* d_out, int out_size, void* d_ws, size_t ws_size,
                              hipStream_t stream) {
  const float* x     = (const float*)d_in[0];  // [4,2048,1024]
  const float* w_qkv = (const float*)d_in[1];  // [1024,3072]
  const float* w_out = (const float*)d_in[2];  // [1024,1024]
  const float* b_out = (const float*)d_in[3];  // [1024]
  float* out = (float*)d_out;                  // [4,2048,1024]

  char* ws = (char*)d_ws;
  unsigned short* xb     = (unsigned short*)ws; ws += (size_t)MTOT * DIM * 2;
  unsigned short* wqkv_t = (unsigned short*)ws; ws += (size_t)NQKV * DIM * 2;
  unsigned short* wout_t = (unsigned short*)ws; ws += (size_t)DIM * DIM * 2;
  unsigned short* qb_    = (unsigned short*)ws; ws += (size_t)BATCH * HEADS * SEQ * DH * 2;
  unsigned short* kb_    = (unsigned short*)ws; ws += (size_t)BATCH * HEADS * SEQ * DH * 2;
  unsigned short* vtb_   = (unsigned short*)ws; ws += (size_t)BATCH * HEADS * SEQ * DH * 2;
  unsigned short* attnb  = (unsigned short*)ws; ws += (size_t)MTOT * DIM * 2;

  // 1. casts / transposes
  cast_f32_bf16<<<(MTOT * DIM / 4 + 255) / 256, 256, 0, stream>>>(x, xb, MTOT * DIM / 4);
  transpose_cast<<<dim3(NQKV / 32, DIM / 32), 256, 0, stream>>>(w_qkv, wqkv_t, DIM, NQKV);
  transpose_cast<<<dim3(DIM / 32, DIM / 32), 256, 0, stream>>>(w_out, wout_t, DIM, DIM);

  // 2. QKV projection — writes Q,K [b,h,n,d] and V TRANSPOSED [b,h,d,n]
  //    (transpose_v kernel eliminated)
  gemm_qkv<<<dim3(NQKV / BN, MTOT / BM), 256, 0, stream>>>(xb, wqkv_t, qb_, kb_, vtb_);

  // 3. flash attention (register-resident P, round-5 proven structure)
  attention<<<dim3(SEQ / 128, HEADS, BATCH), 256, 0, stream>>>(qb_, kb_, vtb_, attnb);

  // 4. output projection + bias
  gemm_out<<<dim3(DIM / BN, MTOT / BM), 256, 0, stream>>>(attnb, wout_t, b_out, out);
}

// Round 8
// 257.012 us; speedup vs baseline: 1.0533x; 1.0303x over previous
//
#include <hip/hip_runtime.h>
#include <cstdint>

#define HEADS 16
#define DH 64
#define SEQ 2048
#define BATCH 4
#define DIM 1024
#define MTOT (BATCH*SEQ)   // 8192
#define NQKV (3*DIM)       // 3072

typedef short bf16x8 __attribute__((ext_vector_type(8)));
typedef float f32x4 __attribute__((ext_vector_type(4)));
typedef float f32x16 __attribute__((ext_vector_type(16)));

__device__ __forceinline__ unsigned short f2bf(float f) {
  union { float fv; unsigned int u; } c; c.fv = f;
  unsigned int u = c.u;
  u += 0x7FFFu + ((u >> 16) & 1u);   // round-to-nearest-even
  return (unsigned short)(u >> 16);
}

// pack two fp32 -> two bf16 in one u32 via HW instruction (1 VALU op vs ~5)
// PROVEN: r1-vs-r4 A/B on attention = 11 us (cvtpk vs manual pack)
__device__ __forceinline__ unsigned int cvtpk(float lo, float hi) {
  unsigned int r;
  asm("v_cvt_pk_bf16_f32 %0, %1, %2" : "=v"(r) : "v"(lo), "v"(hi));
  return r;
}

__device__ __forceinline__ f32x4 mfma16(bf16x8 a, bf16x8 b, f32x4 c) {
  return __builtin_amdgcn_mfma_f32_16x16x32_bf16(a, b, c, 0, 0, 0);
}
__device__ __forceinline__ f32x16 mfma32(bf16x8 a, bf16x8 b, f32x16 c) {
  return __builtin_amdgcn_mfma_f32_32x32x16_bf16(a, b, c, 0, 0, 0);
}

typedef const __attribute__((address_space(1))) unsigned int* gas_ptr;
typedef __attribute__((address_space(3))) unsigned int* las_ptr;
__device__ __forceinline__ void gl2lds16(const void* g, void* l) {
  __builtin_amdgcn_global_load_lds((gas_ptr)g, (las_ptr)l, 16, 0, 0);
}

// Q pre-scale: Dh^-0.5 * log2(e)  (softmax done in exp2 domain)
#define QSCALE 0.18033688011112042f

// ---------------------------------------------------------------- cast x -> bf16
__global__ __launch_bounds__(256) void cast_f32_bf16(
    const float* __restrict__ in, unsigned short* __restrict__ out, int n4) {
  int i = blockIdx.x * blockDim.x + threadIdx.x;
  if (i >= n4) return;
  float4 v = reinterpret_cast<const float4*>(in)[i];
  uint2 o;
  o.x = (unsigned int)f2bf(v.x) | ((unsigned int)f2bf(v.y) << 16);
  o.y = (unsigned int)f2bf(v.z) | ((unsigned int)f2bf(v.w) << 16);
  reinterpret_cast<uint2*>(out)[i] = o;
}

// ------------------------------------------- transpose+cast: out[c][r] = in[r][c]
__global__ __launch_bounds__(256) void transpose_cast(
    const float* __restrict__ in, unsigned short* __restrict__ out, int R, int C) {
  __shared__ float tile[32][33];
  int c0 = blockIdx.x * 32, r0 = blockIdx.y * 32;
  int tx = threadIdx.x & 31, ty = threadIdx.x >> 5;  // ty 0..7
  for (int i = 0; i < 32; i += 8)
    tile[ty + i][tx] = in[(size_t)(r0 + ty + i) * C + c0 + tx];
  __syncthreads();
  for (int i = 0; i < 32; i += 8)
    out[(size_t)(c0 + ty + i) * R + r0 + tx] = f2bf(tile[tx][ty + i]);
}

// ---------------------------------------------------------------- QKV GEMM
// r5-proven: m97 structure, BK=64, XOR-swizzled tiles (both-sides pattern),
// hoisted epilogue. V written TRANSPOSED [b,h,d,n] directly (no transpose_v
// kernel). ROUND-8: V stores routed through a per-wave LDS transpose tile so
// the global stores are 64B-coalesced uint4 runs (r7's direct 8B stores
// touched 64 cache lines per instruction — measured wash vs r5).
#define BM 128
#define BN 128
#define BK 64

__global__ __launch_bounds__(256) void gemm_qkv(
    const unsigned short* __restrict__ A, const unsigned short* __restrict__ Bt,
    unsigned short* __restrict__ Q, unsigned short* __restrict__ K,
    unsigned short* __restrict__ V) {
  __shared__ unsigned short sA[BM * BK];
  __shared__ unsigned short sB[BN * BK];
  const int KD = 1024;
  // XCD-bijective swizzle (nwg = 24*64 = 1536, %8==0)
  int gid = blockIdx.x + 24 * blockIdx.y;      // gridDim.x == 24
  int swz = (gid & 7) * 192 + (gid >> 3);      // cpx = 1536/8
  int m0 = (swz / 24) * BM;
  int n0 = (swz % 24) * BN;
  int t = threadIdx.x;
  int lane = t & 63, w = t >> 6;
  int wm = (w >> 1) * 64, wn = (w & 1) * 64;
  int fr = lane & 15, fg = lane >> 4;

  // staging: wave w, issue i covers rows i*32 + w*8 + (lane>>3);
  // global col chunk = (lane&7) ^ (lane>>3)  (pre-swizzled source)
  int srow = w * 8 + (lane >> 3);
  int scol = ((lane & 7) ^ (lane >> 3)) * 8;
  const unsigned short* gA = &A[(size_t)(m0 + srow) * KD + scol];
  const unsigned short* gB = &Bt[(size_t)(n0 + srow) * KD + scol];
  char* lA = (char*)sA + w * 1024;   // + i*4096 per issue; lane*16 implicit
  char* lB = (char*)sB + w * 1024;

  f32x4 acc[4][4];
#pragma unroll
  for (int i = 0; i < 4; i++)
#pragma unroll
    for (int j = 0; j < 4; j++) { f32x4 z = {0.f, 0.f, 0.f, 0.f}; acc[i][j] = z; }

  for (int k0 = 0; k0 < KD; k0 += BK) {
#pragma unroll
    for (int i = 0; i < 4; i++) {
      gl2lds16(gA + (size_t)i * 32 * KD + k0, lA + i * 4096);
      gl2lds16(gB + (size_t)i * 32 * KD + k0, lB + i * 4096);
    }
    __syncthreads();
#pragma unroll
    for (int ks = 0; ks < 2; ks++) {
      bf16x8 af[4], bfr[4];
#pragma unroll
      for (int mt = 0; mt < 4; mt++)
        af[mt] = *reinterpret_cast<const bf16x8*>(
            &sA[(wm + mt * 16 + fr) * BK + (((ks * 4 + fg) ^ (fr & 7)) * 8)]);
#pragma unroll
      for (int nt = 0; nt < 4; nt++)
        bfr[nt] = *reinterpret_cast<const bf16x8*>(
            &sB[(wn + nt * 16 + fr) * BK + (((ks * 4 + fg) ^ (fr & 7)) * 8)]);
#pragma unroll
      for (int mt = 0; mt < 4; mt++)
#pragma unroll
        for (int nt = 0; nt < 4; nt++)
          acc[mt][nt] = mfma16(af[mt], bfr[nt], acc[mt][nt]);
    }
    __syncthreads();
  }
  // NOTE: final __syncthreads above -> all waves done with sA/sB; safe to
  // reuse sA/sB as per-wave epilogue scratch below.

  // epilogue: Q,K -> [b][h][n][d]; V -> TRANSPOSED [b][h][d][n]
  int rowq = fg * 4;
  int b = m0 >> 11;                       // block-uniform (BM=128 | 2048)
  int nrow0 = (m0 & 2047) + wm + rowq;    // + mt*16, no wrap within block
#pragma unroll
  for (int nt = 0; nt < 4; nt++) {
    int ncb = n0 + wn + nt * 16;          // lane-uniform column base
    int which = ncb >> 10;                // uniform: fr<16 can't cross 1024
    int hdb = ncb & 1023;
    int hh = hdb >> 6;                    // uniform: (n0+wn)%64==0
    if (which == 2) {
      // V^T path: assemble wave's 16(d) x 64(m) subtile in LDS, then
      // 64B-coalesced uint4 stores. Tile 16x72 shorts (rows 144B, 16B-aligned;
      // write conflicts 2-way = free; reads min-conflict). Per-wave private,
      // within-wave ds ordering suffices (no barrier). Alternate sA/sB per nt.
      unsigned short* tw = ((nt & 1) ? sB : sA) + w * 1152;
#pragma unroll
      for (int mt = 0; mt < 4; mt++) {
        f32x4 av = acc[mt][nt];
        uint2 pk;
        pk.x = cvtpk(av[0], av[1]);
        pk.y = cvtpk(av[2], av[3]);
        // d = fr, m-local = mt*16 + fg*4 + {0..3}
        *(uint2*)&tw[fr * 72 + mt * 16 + fg * 4] = pk;
      }
      int dr = lane >> 2, sg = lane & 3;   // 16 d-rows x 4 lanes (8-short segs)
      size_t vrow = ((size_t)(b * HEADS + hh) * DH + nt * 16 + dr) * SEQ
                  + (m0 & 2047) + wm + sg * 8;
#pragma unroll
      for (int it = 0; it < 2; it++) {
        uint4 vv = *(const uint4*)&tw[dr * 72 + sg * 8 + it * 32];
        *(uint4*)&V[vrow + it * 32] = vv;
      }
    } else {
      int dcol = (hdb & 63) + fr;
      unsigned short* dst = (which == 0) ? Q : K;
      size_t cbase = ((size_t)(b * HEADS + hh) * SEQ) * DH + dcol;
#pragma unroll
      for (int mt = 0; mt < 4; mt++) {
        f32x4 av = acc[mt][nt];
        if (which == 0) {                 // uniform branch (Q pre-scale)
          av[0] *= QSCALE; av[1] *= QSCALE; av[2] *= QSCALE; av[3] *= QSCALE;
        }
        size_t idx = cbase + (size_t)(nrow0 + mt * 16) * DH;
        unsigned int u0 = cvtpk(av[0], av[1]);
        unsigned int u1 = cvtpk(av[2], av[3]);
        dst[idx]          = (unsigned short)u0;
        dst[idx + DH]     = (unsigned short)(u0 >> 16);
        dst[idx + 2 * DH] = (unsigned short)u1;
        dst[idx + 3 * DH] = (unsigned short)(u1 >> 16);
      }
    }
  }
}

// ---------------------------------------------------------------- out-proj GEMM
__global__ __launch_bounds__(256) void gemm_out(
    const unsigned short* __restrict__ A, const unsigned short* __restrict__ Bt,
    const float* __restrict__ bias, float* __restrict__ C) {
  __shared__ unsigned short sA[BM * BK];
  __shared__ unsigned short sB[BN * BK];
  const int KD = 1024;
  // XCD-bijective swizzle (nwg = 8*64 = 512, %8==0)
  int gid = blockIdx.x + 8 * blockIdx.y;       // gridDim.x == 8
  int swz = (gid & 7) * 64 + (gid >> 3);       // cpx = 512/8
  int m0 = (swz / 8) * BM;
  int n0 = (swz % 8) * BN;
  int t = threadIdx.x;
  int lane = t & 63, w = t >> 6;
  int wm = (w >> 1) * 64, wn = (w & 1) * 64;
  int fr = lane & 15, fg = lane >> 4;

  int srow = w * 8 + (lane >> 3);
  int scol = ((lane & 7) ^ (lane >> 3)) * 8;
  const unsigned short* gA = &A[(size_t)(m0 + srow) * KD + scol];
  const unsigned short* gB = &Bt[(size_t)(n0 + srow) * KD + scol];
  char* lA = (char*)sA + w * 1024;
  char* lB = (char*)sB + w * 1024;

  f32x4 acc[4][4];
#pragma unroll
  for (int i = 0; i < 4; i++)
#pragma unroll
    for (int j = 0; j < 4; j++) { f32x4 z = {0.f, 0.f, 0.f, 0.f}; acc[i][j] = z; }

  for (int k0 = 0; k0 < KD; k0 += BK) {
#pragma unroll
    for (int i = 0; i < 4; i++) {
      gl2lds16(gA + (size_t)i * 32 * KD + k0, lA + i * 4096);
      gl2lds16(gB + (size_t)i * 32 * KD + k0, lB + i * 4096);
    }
    __syncthreads();
#pragma unroll
    for (int ks = 0; ks < 2; ks++) {
      bf16x8 af[4], bfr[4];
#pragma unroll
      for (int mt = 0; mt < 4; mt++)
        af[mt] = *reinterpret_cast<const bf16x8*>(
            &sA[(wm + mt * 16 + fr) * BK + (((ks * 4 + fg) ^ (fr & 7)) * 8)]);
#pragma unroll
      for (int nt = 0; nt < 4; nt++)
        bfr[nt] = *reinterpret_cast<const bf16x8*>(
            &sB[(wn + nt * 16 + fr) * BK + (((ks * 4 + fg) ^ (fr & 7)) * 8)]);
#pragma unroll
      for (int mt = 0; mt < 4; mt++)
#pragma unroll
        for (int nt = 0; nt < 4; nt++)
          acc[mt][nt] = mfma16(af[mt], bfr[nt], acc[mt][nt]);
    }
    __syncthreads();
  }

  // epilogue: hoisted addressing; bias loaded once per nt
  int rowq = (lane >> 4) * 4;
#pragma unroll
  for (int nt = 0; nt < 4; nt++) {
    int ncol = n0 + wn + nt * 16 + fr;
    float bb = bias[ncol];
    size_t cb = (size_t)(m0 + wm + rowq) * DIM + ncol;
#pragma unroll
    for (int mt = 0; mt < 4; mt++)
#pragma unroll
      for (int r = 0; r < 4; r++)
        C[cb + (size_t)(mt * 16 + r) * DIM] = acc[mt][nt][r] + bb;
  }
}

// ---------------------------------------------------------------- flash attention
// ROUND-5 structure (80-82 us proven) + T5 setprio around MFMA clusters
// (m191: +4-7% when multiple independent blocks share a CU; we have 4/CU).
#define LDA 68

__global__ __launch_bounds__(256, 4) void attention(
    const unsigned short* __restrict__ Qg, const unsigned short* __restrict__ Kg,
    const unsigned short* __restrict__ Vtg, unsigned short* __restrict__ Og) {
  __shared__ unsigned short smem[2 * 64 * 72];   // 18432 B
  unsigned short* sK  = smem;
  unsigned short* sVt = smem + 64 * LDA;

  int gid = blockIdx.x + 16 * (blockIdx.y + 16 * blockIdx.z);  // 0..1023
  int qb   = (gid >> 3) & 15;
  int pair = ((gid & 7) << 3) | (gid >> 7);   // xcd*8 + group
  int h = pair & 15, b = pair >> 4;

  size_t base = (size_t)(b * HEADS + h) * SEQ * DH;
  const unsigned short* Q = Qg + base;
  const unsigned short* K = Kg + base;
  const unsigned short* Vt = Vtg + base;
  int t = threadIdx.x, lane = t & 63, w = t >> 6;
  int m = lane & 31, kh = lane >> 5;
  int q0 = qb * 128 + w * 32;

  bf16x8 qf[4];
#pragma unroll
  for (int kt = 0; kt < 4; kt++)
    qf[kt] = *reinterpret_cast<const bf16x8*>(
        &Q[(size_t)(q0 + m) * DH + kt * 16 + kh * 8]);

  f32x16 oaccT[2];   // [dhalf], C layout: row=d', col=qrow
#pragma unroll
  for (int dh = 0; dh < 2; dh++)
#pragma unroll
    for (int i = 0; i < 16; i++) oaccT[dh][i] = 0.f;
  float rs = 0.f;

  int sr = t >> 2, sc = (t & 3) * 8;

  for (int j0 = 0; j0 < SEQ; j0 += 64) {
    {
      uint4 a0 = *(const uint4*)&K[(size_t)(j0 + sr) * DH + sc];
      uint4 a1 = *(const uint4*)&K[(size_t)(j0 + sr) * DH + sc + 32];
      uint4 b0 = *(const uint4*)&Vt[(size_t)sr * SEQ + j0 + sc];
      uint4 b1 = *(const uint4*)&Vt[(size_t)sr * SEQ + j0 + sc + 32];
      unsigned short* pk0 = &sK[sr * LDA + sc];
      unsigned short* pk1 = &sK[sr * LDA + sc + 32];
      unsigned short* pv0 = &sVt[sr * LDA + sc];
      unsigned short* pv1 = &sVt[sr * LDA + sc + 32];
      *(uint2*)pk0       = make_uint2(a0.x, a0.y);
      *(uint2*)(pk0 + 4) = make_uint2(a0.z, a0.w);
      *(uint2*)pk1       = make_uint2(a1.x, a1.y);
      *(uint2*)(pk1 + 4) = make_uint2(a1.z, a1.w);
      *(uint2*)pv0       = make_uint2(b0.x, b0.y);
      *(uint2*)(pv0 + 4) = make_uint2(b0.z, b0.w);
      *(uint2*)pv1       = make_uint2(b1.x, b1.y);
      *(uint2*)(pv1 + 4) = make_uint2(b1.z, b1.w);
    }
    __syncthreads();

    unsigned int pp[8][2];
#pragma unroll
    for (int jt = 0; jt < 2; jt++) {
      bf16x8 kf[4];
#pragma unroll
      for (int kt = 0; kt < 4; kt++) {
        union { uint2 u[2]; bf16x8 v; } kc;
        const unsigned short* p = &sK[(jt * 32 + m) * LDA + (2 * kt + kh) * 8];
        kc.u[0] = *(const uint2*)p;
        kc.u[1] = *(const uint2*)(p + 4);
        kf[kt] = kc.v;
      }
      f32x16 s;
#pragma unroll
      for (int i = 0; i < 16; i++) s[i] = 0.f;
      __builtin_amdgcn_s_setprio(1);
#pragma unroll
      for (int kt = 0; kt < 4; kt++)
        s = mfma32(kf[kt], qf[kt], s);
      __builtin_amdgcn_s_setprio(0);
      float e[16];
#pragma unroll
      for (int i = 0; i < 16; i++) e[i] = __builtin_amdgcn_exp2f(s[i]);
      float t0 = (e[0] + e[1]) + (e[2] + e[3]);
      float t1 = (e[4] + e[5]) + (e[6] + e[7]);
      float t2 = (e[8] + e[9]) + (e[10] + e[11]);
      float t3 = (e[12] + e[13]) + (e[14] + e[15]);
      rs += (t0 + t1) + (t2 + t3);
#pragma unroll
      for (int sl = 0; sl < 4; sl++) {
        pp[4 * jt + sl][0] = cvtpk(e[4 * sl + 0], e[4 * sl + 1]);
        pp[4 * jt + sl][1] = cvtpk(e[4 * sl + 2], e[4 * sl + 3]);
      }
    }

    __builtin_amdgcn_s_setprio(1);
#pragma unroll
    for (int kb = 0; kb < 4; kb++) {
#pragma unroll
      for (int dh = 0; dh < 2; dh++) {
        union { uint2 u[2]; bf16x8 v; } ac;
        const unsigned short* p = &sVt[(32 * dh + m) * LDA + 16 * kb + 4 * kh];
        ac.u[0] = *(const uint2*)p;
        ac.u[1] = *(const uint2*)(p + 8);
        union { unsigned int u[4]; bf16x8 v; } bc;
        bc.u[0] = pp[2 * kb][0];
        bc.u[1] = pp[2 * kb][1];
        bc.u[2] = pp[2 * kb + 1][0];
        bc.u[3] = pp[2 * kb + 1][1];
        oaccT[dh] = mfma32(ac.v, bc.v, oaccT[dh]);
      }
    }
    __builtin_amdgcn_s_setprio(0);
    __syncthreads();
  }

  float inv;
  {
    float tot = rs + __shfl_xor(rs, 32);
    inv = 1.0f / tot;
  }

  unsigned int* ew = (unsigned int*)smem + (size_t)w * 32 * 36;
#pragma unroll
  for (int dh = 0; dh < 2; dh++)
#pragma unroll
    for (int sl = 0; sl < 4; sl++) {
      unsigned int u0 = cvtpk(oaccT[dh][4 * sl + 0] * inv, oaccT[dh][4 * sl + 1] * inv);
      unsigned int u1 = cvtpk(oaccT[dh][4 * sl + 2] * inv, oaccT[dh][4 * sl + 3] * inv);
      uint2 pk; pk.x = u0; pk.y = u1;
      *(uint2*)&ew[m * 36 + 16 * dh + 4 * sl + 2 * kh] = pk;
    }
  {
    int mr = lane >> 3, ch = lane & 7;
#pragma unroll
    for (int it = 0; it < 4; it++) {
      uint4 vv = *(const uint4*)&ew[(8 * it + mr) * 36 + ch * 4];
      int n = q0 + 8 * it + mr;
      *(uint4*)&Og[((size_t)(b * SEQ + n)) * DIM + h * DH + ch * 8] = vv;
    }
  }
}

// ---------------------------------------------------------------- launch
extern "C" void kernel_launch(void* const* d_in, const int* in_sizes, int n_in,
                              void* d_out, int out_size, void* d_ws, size_t ws_size,
                              hipStream_t stream) {
  const float* x     = (const float*)d_in[0];  // [4,2048,1024]
  const float* w_qkv = (const float*)d_in[1];  // [1024,3072]
  const float* w_out = (const float*)d_in[2];  // [1024,1024]
  const float* b_out = (const float*)d_in[3];  // [1024]
  float* out = (float*)d_out;                  // [4,2048,1024]

  char* ws = (char*)d_ws;
  unsigned short* xb     = (unsigned short*)ws; ws += (size_t)MTOT * DIM * 2;
  unsigned short* wqkv_t = (unsigned short*)ws; ws += (size_t)NQKV * DIM * 2;
  unsigned short* wout_t = (unsigned short*)ws; ws += (size_t)DIM * DIM * 2;
  unsigned short* qb_    = (unsigned short*)ws; ws += (size_t)BATCH * HEADS * SEQ * DH * 2;
  unsigned short* kb_    = (unsigned short*)ws; ws += (size_t)BATCH * HEADS * SEQ * DH * 2;
  unsigned short* vtb_   = (unsigned short*)ws; ws += (size_t)BATCH * HEADS * SEQ * DH * 2;
  unsigned short* attnb  = (unsigned short*)ws; ws += (size_t)MTOT * DIM * 2;

  // 1. casts / transposes
  cast_f32_bf16<<<(MTOT * DIM / 4 + 255) / 256, 256, 0, stream>>>(x, xb, MTOT * DIM / 4);
  transpose_cast<<<dim3(NQKV / 32, DIM / 32), 256, 0, stream>>>(w_qkv, wqkv_t, DIM, NQKV);
  transpose_cast<<<dim3(DIM / 32, DIM / 32), 256, 0, stream>>>(w_out, wout_t, DIM, DIM);

  // 2. QKV projection — Q,K [b,h,n,d]; V TRANSPOSED [b,h,d,n] via LDS-coalesced
  //    epilogue (transpose_v kernel eliminated, stores 64B-coalesced)
  gemm_qkv<<<dim3(NQKV / BN, MTOT / BM), 256, 0, stream>>>(xb, wqkv_t, qb_, kb_, vtb_);

  // 3. flash attention (register-resident P, r5 structure + setprio)
  attention<<<dim3(SEQ / 128, HEADS, BATCH), 256, 0, stream>>>(qb_, kb_, vtb_, attnb);

  // 4. output projection + bias
  gemm_out<<<dim3(DIM / BN, MTOT / BM), 256, 0, stream>>>(attnb, wout_t, b_out, out);
}